// Round 8
// baseline (1170.463 us; speedup 1.0000x reference)
//
#include <hip/hip_runtime.h>
#include <hip/hip_fp16.h>
#include <math.h>

#define NODES   100000
#define EDGES   1200000
#define GRAPHS  512
#define DIM     64
#define NT      10
#define KTOT    576     // 64 base + 64*8 spline features

#define NB      512     // sort buckets: bucket = dst >> 8; 391 populated
#define NBUSED  391     // populated buckets = ceil(NODES/256)
#define EPB     4096    // edges per s3 block
// CAP: populated-bucket mean = 1.2M/391 = 3070 (sigma ~55) -> 4608 slab.
#define CAP     4608

// K-chunked weight staging: 9 stages x 64 k-values (2 MFMA steps each)
#define KSTAGE     64
#define WTL_STRIDE 72   // 64 shorts + 8 pad
#define V_STRIDEF  68   // fp32 v row stride (64 + 4 pad -> 2-way banks only)

// mega-kernel block ranges (512 threads each)
#define S3B     ((EDGES + EPB - 1) / EPB)              // 293
#define PREPB   ((2 * DIM * KTOT) / 512)               // 144
#define CONVB   ((NODES * 16 + 32 + 511) / 512)        // 3126

// Lessons ledger:
//  R6: global-atomic CSR scatter = ~100us (16x line amplification on 4B
//      random writes + serialized cursor atomics).  Keep the LDS bucket sort.
//  R7: scan micro-opts null -> s4's cost is the tmp->col round trip itself,
//      not the scans.  This round removes s4 by consuming raw slabs.
//  R2-4: device-scope fp32 atomic pooling (1.6M on 32K addrs) costs ~22us;
//      tight launch-bounds min-waves collapse regalloc (64-VGPR cap -> 32).

typedef _Float16 f16x8  __attribute__((ext_vector_type(8)));   // MFMA A/B frag
typedef __fp16   fp16x2 __attribute__((ext_vector_type(2)));   // cvt_pkrtz result
typedef __attribute__((ext_vector_type(4))) float frag_cd;     // 4 fp32 acc

__device__ __forceinline__ float silu(float x) {
    return x * __builtin_amdgcn_rcpf(1.f + __expf(-x));
}

__device__ __forceinline__ unsigned packh2(float a, float b) {
    fp16x2 h = __builtin_amdgcn_cvt_pkrtz(a, b);
    return __builtin_bit_cast(unsigned, h);
}

// 8 packed fp16 viewed as 4 half2
union H8 { uint4 u; __half2 h[4]; };

// ---------------------------------------------------------------------------
// Cubic B-spline bases for one dim as packed fp16x8 A-fragment.
// ---------------------------------------------------------------------------
__device__ __forceinline__ f16x8 bases_frag(float xv) {
    float tt  = fmaf(xv, 2.5f, 5.5f);
    float fm  = floorf(tt);
    int   m   = (int)fm;
    float u   = tt - fm;
    float u2  = u * u;
    float u3  = u2 * u;
    float v0  = fmaf(fmaf(fmaf(u, -(1.f / 6.f), 0.5f), u, -0.5f), u, 1.f / 6.f); // (1-u)^3/6
    float v1  = fmaf(u3, 0.5f, fmaf(u2, -1.f, 2.f / 3.f));                       // (3u^3-6u^2+4)/6
    float v2  = fmaf(u + u2 - u3, 0.5f, 1.f / 6.f);                              // (-3u^3+3u^2+3u+1)/6
    float v3  = u3 * (1.f / 6.f);

    unsigned d0 = packh2(v0, v1);
    unsigned d1 = packh2(v2, v3);
    int p = m - 3;
    int B = p >> 1;
    bool odd = (p & 1) != 0;
    unsigned e1 = __builtin_amdgcn_alignbit(d1, d0, 16);   // [v1,v2]
    unsigned W0 = odd ? (d0 << 16) : d0;
    unsigned W1 = odd ? e1 : d1;
    unsigned W2 = odd ? (d1 >> 16) : 0u;
    union { f16x8 f; unsigned u[4]; } r;
    r.u[0] = (B == 0) ? W0 : ((B == -1) ? W1 : ((B == -2) ? W2 : 0u));
    r.u[1] = (B == 1) ? W0 : ((B ==  0) ? W1 : ((B == -1) ? W2 : 0u));
    r.u[2] = (B == 2) ? W0 : ((B ==  1) ? W1 : ((B ==  0) ? W2 : 0u));
    r.u[3] = (B == 3) ? W0 : ((B ==  2) ? W1 : ((B ==  1) ? W2 : 0u));
    return r.f;
}

// ===========================================================================
// Mega kernel: three independent phases by block range (512 threads each).
//   [0, S3B)               : s3 edge partition with LDS local sort -> tmp
//   [S3B, S3B+PREPB)       : fp16 W_T prep for both layers
//   [S3B+PREPB, +CONVB)    : x fp32->fp16 conv + pad rows + graph offsets
// ===========================================================================
__global__ __launch_bounds__(512) void mega(const int* __restrict__ ei,
                                            int* __restrict__ bcur,
                                            unsigned* __restrict__ tmp,
                                            const float* __restrict__ bw0,
                                            const float* __restrict__ sw0,
                                            const float* __restrict__ sc0,
                                            const float* __restrict__ bw1,
                                            const float* __restrict__ sw1,
                                            const float* __restrict__ sc1,
                                            unsigned short* __restrict__ wt0,
                                            unsigned short* __restrict__ wt1,
                                            const float* __restrict__ x,
                                            const int* __restrict__ bat,
                                            unsigned short* __restrict__ xb,
                                            unsigned short* __restrict__ hpad,
                                            int* __restrict__ goff) {
    __shared__ int hist[NB], lstart[NB], gbase[NB], cur[NB];   // 8 KB
    __shared__ int wsum8[8];
    __shared__ unsigned ebuf[EPB];                             // 16 KB
    __shared__ unsigned short bk[EPB];                         //  8 KB
    const int bx = blockIdx.x;
    const int t  = threadIdx.x;

    if (bx < S3B) {
        // ---- s3: partition EPB edges into bucket slabs, LDS-local sort ----
        hist[t] = 0; cur[t] = 0;
        __syncthreads();
        const int e0 = bx * EPB;
        int src[8], dst[8];
#pragma unroll
        for (int k = 0; k < 8; ++k) {
            int e = e0 + t + k * 512;
            bool valid = e < EDGES;
            src[k] = valid ? ei[e] : 0;
            dst[k] = valid ? ei[EDGES + e] : -1;
            if (valid) atomicAdd(&hist[dst[k] >> 8], 1);
        }
        __syncthreads();
        // exclusive scan of hist -> lstart: wave shfl scan + 8 partials
        int v = hist[t];
        int incl = v;
#pragma unroll
        for (int off = 1; off < 64; off <<= 1) {
            int u = __shfl_up(incl, off, 64);
            if ((t & 63) >= off) incl += u;
        }
        if ((t & 63) == 63) wsum8[t >> 6] = incl;
        __syncthreads();
        {
            int wid = t >> 6, wpre = 0;
#pragma unroll
            for (int k = 0; k < 7; ++k) if (k < wid) wpre += wsum8[k];
            lstart[t] = wpre + incl - v;
        }
        // global reservation
        if (v) gbase[t] = atomicAdd(&bcur[t], v);
        __syncthreads();
        // scatter regs -> LDS (bucket-contiguous)
#pragma unroll
        for (int k = 0; k < 8; ++k) {
            if (dst[k] >= 0) {
                int b = dst[k] >> 8;
                int pos = lstart[b] + atomicAdd(&cur[b], 1);
                ebuf[pos] = (unsigned)src[k] | ((unsigned)(dst[k] & 255) << 24);
                bk[pos] = (unsigned short)b;
            }
        }
        __syncthreads();
        // linear sweep: consecutive i -> consecutive slab addresses
        int total = EDGES - e0; if (total > EPB) total = EPB;
        for (int i = t; i < total; i += 512) {
            int b = bk[i];
            tmp[(size_t)b * CAP + gbase[b] + (i - lstart[b])] = ebuf[i];
        }
        return;
    }

    if (bx < S3B + PREPB) {
        // ---- weight prep ----
        int idx = (bx - S3B) * 512 + t;
        int layer = idx >= DIM * KTOT;
        int li = layer ? idx - DIM * KTOT : idx;
        const float* bw = layer ? bw1 : bw0;
        const float* sw = layer ? sw1 : sw0;
        const float* sc = layer ? sc1 : sc0;
        unsigned short* wt = layer ? wt1 : wt0;
        int o = li / KTOT, k = li % KTOT;
        float v;
        if (k < DIM) {
            v = bw[o * DIM + k];
        } else {
            int i = (k - DIM) >> 3, g = (k - DIM) & 7;
            v = sw[(o * DIM + i) * 8 + g] * sc[o * DIM + i];
        }
        wt[li] = __half_as_ushort(__float2half(v));
        return;
    }

    // ---- conv: x fp32 -> fp16, pad rows, graph offsets ----
    int i = (bx - S3B - PREPB) * 512 + t;
    if (i < NODES * 16) {
        float4 v = ((const float4*)x)[i];
        unsigned lo = packh2(v.x, v.y);
        unsigned hi = packh2(v.z, v.w);
        ((uint2*)xb)[i] = make_uint2(lo, hi);
        if ((i & 15) == 0) {
            int n = i >> 4;
            int b  = bat[n];
            int bp = (n == 0) ? -1 : bat[n - 1];
            for (int g = bp + 1; g <= b; ++g) goff[g] = n;
        }
        if (i == 0) {
            int blast = bat[NODES - 1];
            for (int g = blast + 1; g <= GRAPHS; ++g) goff[g] = NODES;
        }
    } else {
        int j = i - NODES * 16;
        if (j < 16)      ((uint2*)xb)[NODES * 16 + j] = make_uint2(0, 0);
        else if (j < 32) ((uint2*)hpad)[j - 16]       = make_uint2(0, 0);
    }
}

// ---------------------------------------------------------------------------
// add one fp16x8 row slice into LDS fp32 via 8 atomicAdds (ds_add_f32).
// Banks: 64 consecutive floats per entry -> exactly 2 lanes/bank (free).
// ---------------------------------------------------------------------------
__device__ __forceinline__ void acc_row(float* dst, uint4 r) {
    H8 h; h.u = r;
#pragma unroll
    for (int k = 0; k < 4; ++k) {
        float2 f = __half22float2(h.h[k]);
        atomicAdd(dst + 2 * k,     f.x);
        atomicAdd(dst + 2 * k + 1, f.y);
    }
}

// ===========================================================================
// fused2: one block per 256-node bucket; consumes the RAW s3 slab (no s4,
// no col/rowp).  Phases: init v (fp32 LDS) from own row -> LDS-atomic
// neighbor accumulation from unsorted slab -> 9-chunk MFMA KAN -> store.
// 8 waves x 2 node-tiles of 16.  LDS 78.8KB -> 2 blocks/CU.
// ===========================================================================
__global__ __launch_bounds__(512, 4) void fused2(const unsigned short* __restrict__ xin,
                                                 const unsigned* __restrict__ tmp,
                                                 const int* __restrict__ bcur,
                                                 const unsigned short* __restrict__ wt,
                                                 unsigned short* __restrict__ out) {
    __shared__ float v[256][V_STRIDEF];                 // 69632 B
    __shared__ unsigned short wt_lds[64 * WTL_STRIDE];  //  9216 B

    const int t = threadIdx.x;
    const int b = blockIdx.x;
    const int nbase = b * 256;
    const uint4* x4 = (const uint4*)xin;

    // ---- stage W chunk 0 (1 uint4/thread, latency hidden under init+acc) --
    uint4 p0 = *(const uint4*)(wt + (t >> 3) * KTOT + (t & 7) * 8);

    // ---- init v: self term (fp16 -> fp32), 2 threads per node ----
    {
        int node = t >> 1, hf = t & 1;
        int n = nbase + node;
        float* vr = v[node] + hf * 32;
        if (n < NODES) {
#pragma unroll
            for (int j = 0; j < 4; ++j) {
                H8 r; r.u = x4[n * 8 + hf * 4 + j];
#pragma unroll
                for (int k = 0; k < 4; ++k) {
                    float2 f = __half22float2(r.h[k]);
                    vr[j * 8 + 2 * k]     = f.x;
                    vr[j * 8 + 2 * k + 1] = f.y;
                }
            }
        } else {
#pragma unroll
            for (int j = 0; j < 32; ++j) vr[j] = 0.f;
        }
    }
    __syncthreads();

    // ---- neighbor accumulation from raw slab: 8 threads/entry, 4 in flight
    {
        const int cnt = bcur[b];
        const size_t base = (size_t)b * CAP;
        const int grp = t >> 3, c8 = t & 7;
        for (int e = grp; e < cnt; e += 256) {
            int e1 = e + 64, e2 = e + 128, e3 = e + 192;
            unsigned w0 = tmp[base + e];
            unsigned w1 = (e1 < cnt) ? tmp[base + e1] : 0u;
            unsigned w2 = (e2 < cnt) ? tmp[base + e2] : 0u;
            unsigned w3 = (e3 < cnt) ? tmp[base + e3] : 0u;
            uint4 r0 = x4[(w0 & 0xFFFFFFu) * 8 + c8];
            uint4 r1 = (e1 < cnt) ? x4[(w1 & 0xFFFFFFu) * 8 + c8] : make_uint4(0, 0, 0, 0);
            uint4 r2 = (e2 < cnt) ? x4[(w2 & 0xFFFFFFu) * 8 + c8] : make_uint4(0, 0, 0, 0);
            uint4 r3 = (e3 < cnt) ? x4[(w3 & 0xFFFFFFu) * 8 + c8] : make_uint4(0, 0, 0, 0);
            acc_row(&v[w0 >> 24][c8 * 8], r0);
            if (e1 < cnt) acc_row(&v[w1 >> 24][c8 * 8], r1);
            if (e2 < cnt) acc_row(&v[w2 >> 24][c8 * 8], r2);
            if (e3 < cnt) acc_row(&v[w3 >> 24][c8 * 8], r3);
        }
    }
    // commit W chunk 0
    *(uint4*)(wt_lds + (t >> 3) * WTL_STRIDE + (t & 7) * 8) = p0;
    __syncthreads();

    // ---- MFMA phase: wave w -> node rows w*32 .. w*32+31 (2 tiles) ----
    const int w = t >> 6;
    const int l = t & 63;
    const int q = l >> 4;            // k-quad
    const int c = l & 15;            // A row (node) / B row (output)
    const int r0w = w * 32 + c;
    const int r1w = w * 32 + 16 + c;

    frag_cd ac00 = {0.f,0.f,0.f,0.f}, ac01 = {0.f,0.f,0.f,0.f};
    frag_cd ac02 = {0.f,0.f,0.f,0.f}, ac03 = {0.f,0.f,0.f,0.f};
    frag_cd ac10 = {0.f,0.f,0.f,0.f}, ac11 = {0.f,0.f,0.f,0.f};
    frag_cd ac12 = {0.f,0.f,0.f,0.f}, ac13 = {0.f,0.f,0.f,0.f};

#define MSTEP2(OFF, A0, A1) {                                                   \
    f16x8 b0 = *(const f16x8*)(wt_lds + (c     ) * WTL_STRIDE + (OFF));         \
    f16x8 b1 = *(const f16x8*)(wt_lds + (c + 16) * WTL_STRIDE + (OFF));         \
    f16x8 b2 = *(const f16x8*)(wt_lds + (c + 32) * WTL_STRIDE + (OFF));         \
    f16x8 b3 = *(const f16x8*)(wt_lds + (c + 48) * WTL_STRIDE + (OFF));         \
    ac00 = __builtin_amdgcn_mfma_f32_16x16x32_f16(A0, b0, ac00, 0, 0, 0);       \
    ac01 = __builtin_amdgcn_mfma_f32_16x16x32_f16(A0, b1, ac01, 0, 0, 0);       \
    ac02 = __builtin_amdgcn_mfma_f32_16x16x32_f16(A0, b2, ac02, 0, 0, 0);       \
    ac03 = __builtin_amdgcn_mfma_f32_16x16x32_f16(A0, b3, ac03, 0, 0, 0);       \
    ac10 = __builtin_amdgcn_mfma_f32_16x16x32_f16(A1, b0, ac10, 0, 0, 0);       \
    ac11 = __builtin_amdgcn_mfma_f32_16x16x32_f16(A1, b1, ac11, 0, 0, 0);       \
    ac12 = __builtin_amdgcn_mfma_f32_16x16x32_f16(A1, b2, ac12, 0, 0, 0);       \
    ac13 = __builtin_amdgcn_mfma_f32_16x16x32_f16(A1, b3, ac13, 0, 0, 0); }

    // prefetch chunk 1
    p0 = *(const uint4*)(wt + (t >> 3) * KTOT + KSTAGE + (t & 7) * 8);

    // chunk 0: silu base features k = 0..63 (2 MFMA steps)
#pragma unroll
    for (int s = 0; s < 2; ++s) {
        const float* a0p = v[r0w] + 32 * s + 8 * q;
        const float* a1p = v[r1w] + 32 * s + 8 * q;
        union { f16x8 f; unsigned u[4]; } A0, A1;
#pragma unroll
        for (int j = 0; j < 4; ++j) {
            A0.u[j] = packh2(silu(a0p[2 * j]), silu(a0p[2 * j + 1]));
            A1.u[j] = packh2(silu(a1p[2 * j]), silu(a1p[2 * j + 1]));
        }
        MSTEP2(32 * s + 8 * q, A0.f, A1.f);
    }

    // chunks 1..8: barrier, commit prefetched chunk, prefetch next, 2 steps
#pragma unroll
    for (int st = 1; st < 9; ++st) {
        __syncthreads();
        *(uint4*)(wt_lds + (t >> 3) * WTL_STRIDE + (t & 7) * 8) = p0;
        __syncthreads();
        if (st < 8)
            p0 = *(const uint4*)(wt + (t >> 3) * KTOT + (st + 1) * KSTAGE + (t & 7) * 8);
#pragma unroll
        for (int k2 = 0; k2 < 2; ++k2) {
            int d = 8 * (st - 1) + 4 * k2 + q;
            f16x8 A0 = bases_frag(v[r0w][d]);
            f16x8 A1 = bases_frag(v[r1w][d]);
            MSTEP2(32 * k2 + 8 * q, A0, A1);
        }
    }
#undef MSTEP2

    // ---- store fp16: rows = nodes, cols = c + 16*acc ----
    {
        const int n0 = nbase + w * 32 + (q << 2);
#pragma unroll
        for (int r = 0; r < 4; ++r) {
            int n = n0 + r;
            if (n < NODES) {
                unsigned short* o = out + (size_t)n * DIM + c;
                o[0]  = __half_as_ushort(__float2half(ac00[r]));
                o[16] = __half_as_ushort(__float2half(ac01[r]));
                o[32] = __half_as_ushort(__float2half(ac02[r]));
                o[48] = __half_as_ushort(__float2half(ac03[r]));
            }
            int n1 = n0 + 16 + r;
            if (n1 < NODES) {
                unsigned short* o = out + (size_t)n1 * DIM + c;
                o[0]  = __half_as_ushort(__float2half(ac10[r]));
                o[16] = __half_as_ushort(__float2half(ac11[r]));
                o[32] = __half_as_ushort(__float2half(ac12[r]));
                o[48] = __half_as_ushort(__float2half(ac13[r]));
            }
        }
    }
}

// ---------------------------------------------------------------------------
// Fused pool + head: one block per graph, uint4 (16B/lane) h-loads.
// ---------------------------------------------------------------------------
__global__ __launch_bounds__(256) void pool_head(const unsigned short* __restrict__ h,
                                                 const int* __restrict__ goff,
                                                 const float* __restrict__ bwh,
                                                 const float* __restrict__ swh,
                                                 const float* __restrict__ sch,
                                                 float* __restrict__ out) {
    __shared__ float red[32][64];
    const int g = blockIdx.x, t = threadIdx.x;
    const int start = goff[g], end = goff[g + 1];
    const int grp = t >> 3, c8 = t & 7;
    const uint4* h4 = (const uint4*)h;

    float f[8];
#pragma unroll
    for (int j = 0; j < 8; ++j) f[j] = 0.f;
    for (int n = start + grp; n < end; n += 32) {
        H8 v; v.u = h4[n * 8 + c8];
#pragma unroll
        for (int j = 0; j < 4; ++j) {
            float2 fj = __half22float2(v.h[j]);
            f[2 * j]     += fj.x;
            f[2 * j + 1] += fj.y;
        }
    }
#pragma unroll
    for (int j = 0; j < 8; ++j) red[grp][c8 * 8 + j] = f[j];
    __syncthreads();

    if (t < 64) {
        const int i = t;
        float xv = 0.f;
#pragma unroll
        for (int k = 0; k < 32; ++k) xv += red[k][i];

        float s  = silu(xv);
        float tt  = fmaf(xv, 2.5f, 5.5f);
        float fm  = floorf(tt);
        int   m   = (int)fm;
        float u   = tt - fm;
        float u2  = u * u;
        float u3  = u2 * u;
        float v0  = fmaf(fmaf(fmaf(u, -(1.f / 6.f), 0.5f), u, -0.5f), u, 1.f / 6.f);
        float v1  = fmaf(u3, 0.5f, fmaf(u2, -1.f, 2.f / 3.f));
        float v2  = fmaf(u + u2 - u3, 0.5f, 1.f / 6.f);
        float v3  = u3 * (1.f / 6.f);
        bool inr  = (m >= 0) && (m <= 10);
        float b[8];
#pragma unroll
        for (int j = 0; j < 8; ++j) {
            float bv = 0.f;
            bv = (j == m - 3) ? v0 : bv;
            bv = (j == m - 2) ? v1 : bv;
            bv = (j == m - 1) ? v2 : bv;
            bv = (j == m)     ? v3 : bv;
            b[j] = inr ? bv : 0.f;
        }

        float part[NT];
#pragma unroll
        for (int o = 0; o < NT; ++o) {
            const float* sp = swh + (o * DIM + i) * 8;
            float sb = 0.f;
#pragma unroll
            for (int qq = 0; qq < 8; ++qq) sb = fmaf(b[qq], sp[qq], sb);
            part[o] = fmaf(s, bwh[o * DIM + i], sb * sch[o * DIM + i]);
        }
#pragma unroll
        for (int o = 0; o < NT; ++o) {
            float v = part[o];
#pragma unroll
            for (int off = 32; off > 0; off >>= 1) v += __shfl_down(v, off, 64);
            if (i == 0) out[g * NT + o] = v;
        }
    }
}

// ---------------------------------------------------------------------------
extern "C" void kernel_launch(void* const* d_in, const int* in_sizes, int n_in,
                              void* d_out, int out_size, void* d_ws, size_t ws_size,
                              hipStream_t stream) {
    const float* x   = (const float*)d_in[0];
    const int*   ei  = (const int*)d_in[1];
    const int*   bat = (const int*)d_in[2];
    const float* bw0 = (const float*)d_in[3];
    const float* sw0 = (const float*)d_in[4];
    const float* sc0 = (const float*)d_in[5];
    const float* bw1 = (const float*)d_in[6];
    const float* sw1 = (const float*)d_in[7];
    const float* sc1 = (const float*)d_in[8];
    const float* bwh = (const float*)d_in[9];
    const float* swh = (const float*)d_in[10];
    const float* sch = (const float*)d_in[11];
    float* out = (float*)d_out;

    const size_t ROW = (size_t)(NODES + 1) * DIM;   // +1 pad row (conv writes it)

    // ---- workspace layout (16B-aligned sections) ----
    unsigned short* wt0 = (unsigned short*)d_ws;                 // 36864 fp16
    unsigned short* wt1 = wt0 + DIM * KTOT;                      // 36864 fp16
    unsigned short* xbf = wt1 + DIM * KTOT;                      // ROW fp16
    unsigned short* hbf = xbf + ROW;                             // ROW fp16 (layer0 out)
    unsigned short* h2  = hbf + ROW;                             // NODES*DIM fp16
    int* goff     = (int*)(h2 + (size_t)NODES * DIM);            // 514 i (padded)
    int* bcur     = goff + 514;                                  // NB i
    unsigned* tmp = (unsigned*)(bcur + NB);                      // NB*CAP u32

    (void)hipMemsetAsync(bcur, 0, NB * sizeof(int), stream);

    mega<<<S3B + PREPB + CONVB, 512, 0, stream>>>(
        ei, bcur, tmp,
        bw0, sw0, sc0, bw1, sw1, sc1, wt0, wt1,
        x, bat, xbf, hbf + (size_t)NODES * DIM, goff);

    fused2<<<NBUSED, 512, 0, stream>>>(xbf, tmp, bcur, wt0, hbf);
    fused2<<<NBUSED, 512, 0, stream>>>(hbf, tmp, bcur, wt1, h2);

    pool_head<<<GRAPHS, 256, 0, stream>>>(h2, goff, bwh, swh, sch, out);
}

// Round 9
// 198.316 us; speedup vs baseline: 5.9020x; 5.9020x over previous
//
#include <hip/hip_runtime.h>
#include <hip/hip_fp16.h>
#include <math.h>

#define NODES   100000
#define EDGES   1200000
#define GRAPHS  512
#define DIM     64
#define NT      10
#define KTOT    576     // 64 base + 64*8 spline features

#define NB      512     // sort buckets: bucket = dst >> 8; 391 populated
#define NBUSED  391     // populated buckets = ceil(NODES/256)
#define EPB     4096    // edges per s3 block
// CAP: populated-bucket mean = 1.2M/391 = 3070 (sigma ~55) + per-node x4
// padding (<= 768) -> 4608 gives ~10 sigma headroom.
#define CAP     4608

// K-chunked weight staging: 9 stages x 64 k-values (2 MFMA steps each)
#define KSTAGE     64
#define WTL_STRIDE 72   // 64 shorts + 8 pad
#define V_STRIDE   72   // padded fp16 row stride for v in LDS

// mega-kernel block ranges (512 threads each)
#define S3B     ((EDGES + EPB - 1) / EPB)              // 293
#define PREPB   ((2 * DIM * KTOT) / 512)               // 144
#define CONVB   ((NODES * 16 + 32 + 511) / 512)        // 3126

// Lessons ledger:
//  R2-4: device-scope fp32 atomic pooling (1.6M on 32K addrs) costs ~22us;
//        tight launch-bounds min-waves args can collapse regalloc.
//  R6:   global-atomic CSR scatter = ~100us (16x line amplification on 4B
//        random writes + serialized cursor atomics).  Keep the LDS bucket sort.
//  R7:   scan micro-opts null -> sort cost is structural, not barriers.
//  R8:   per-edge LDS fp32 atomicAdd gather = 529us/layer (ds-atomic RMW
//        serialization, 2 blocks/CU).  Sorted segments + per-thread register
//        accumulation is the proven gather form -- do not replace it.

typedef _Float16 f16x8  __attribute__((ext_vector_type(8)));   // MFMA A/B frag
typedef __fp16   fp16x2 __attribute__((ext_vector_type(2)));   // cvt_pkrtz result
typedef __attribute__((ext_vector_type(4))) float frag_cd;     // 4 fp32 acc

__device__ __forceinline__ float silu(float x) {
    return x * __builtin_amdgcn_rcpf(1.f + __expf(-x));
}

__device__ __forceinline__ unsigned packh2(float a, float b) {
    fp16x2 h = __builtin_amdgcn_cvt_pkrtz(a, b);
    return __builtin_bit_cast(unsigned, h);
}

// 8 packed fp16 viewed as 4 half2 for v_pk_add_f16 accumulation
union H8 { uint4 u; __half2 h[4]; };

// ---------------------------------------------------------------------------
// Cubic B-spline bases for one dim as packed fp16x8 A-fragment.
// ---------------------------------------------------------------------------
__device__ __forceinline__ f16x8 bases_frag(float xv) {
    float tt  = fmaf(xv, 2.5f, 5.5f);
    float fm  = floorf(tt);
    int   m   = (int)fm;
    float u   = tt - fm;
    float u2  = u * u;
    float u3  = u2 * u;
    float v0  = fmaf(fmaf(fmaf(u, -(1.f / 6.f), 0.5f), u, -0.5f), u, 1.f / 6.f); // (1-u)^3/6
    float v1  = fmaf(u3, 0.5f, fmaf(u2, -1.f, 2.f / 3.f));                       // (3u^3-6u^2+4)/6
    float v2  = fmaf(u + u2 - u3, 0.5f, 1.f / 6.f);                              // (-3u^3+3u^2+3u+1)/6
    float v3  = u3 * (1.f / 6.f);

    unsigned d0 = packh2(v0, v1);
    unsigned d1 = packh2(v2, v3);
    int p = m - 3;
    int B = p >> 1;
    bool odd = (p & 1) != 0;
    unsigned e1 = __builtin_amdgcn_alignbit(d1, d0, 16);   // [v1,v2]
    unsigned W0 = odd ? (d0 << 16) : d0;
    unsigned W1 = odd ? e1 : d1;
    unsigned W2 = odd ? (d1 >> 16) : 0u;
    union { f16x8 f; unsigned u[4]; } r;
    r.u[0] = (B == 0) ? W0 : ((B == -1) ? W1 : ((B == -2) ? W2 : 0u));
    r.u[1] = (B == 1) ? W0 : ((B ==  0) ? W1 : ((B == -1) ? W2 : 0u));
    r.u[2] = (B == 2) ? W0 : ((B ==  1) ? W1 : ((B ==  0) ? W2 : 0u));
    r.u[3] = (B == 3) ? W0 : ((B ==  2) ? W1 : ((B ==  1) ? W2 : 0u));
    return r.f;
}

// ===========================================================================
// Mega kernel: three independent phases by block range (512 threads each).
//   [0, S3B)               : s3 edge partition with LDS local sort
//   [S3B, S3B+PREPB)       : fp16 W_T prep for both layers
//   [S3B+PREPB, +CONVB)    : x fp32->fp16 conv + pad rows + graph offsets
// ===========================================================================
__global__ __launch_bounds__(512) void mega(const int* __restrict__ ei,
                                            int* __restrict__ bcur,
                                            unsigned* __restrict__ tmp,
                                            const float* __restrict__ bw0,
                                            const float* __restrict__ sw0,
                                            const float* __restrict__ sc0,
                                            const float* __restrict__ bw1,
                                            const float* __restrict__ sw1,
                                            const float* __restrict__ sc1,
                                            unsigned short* __restrict__ wt0,
                                            unsigned short* __restrict__ wt1,
                                            const float* __restrict__ x,
                                            const int* __restrict__ bat,
                                            unsigned short* __restrict__ xb,
                                            unsigned short* __restrict__ hpad,
                                            int* __restrict__ goff) {
    __shared__ int hist[NB], lstart[NB], gbase[NB], cur[NB];   // 8 KB
    __shared__ int wsum8[8];
    __shared__ unsigned ebuf[EPB];                             // 16 KB
    __shared__ unsigned short bk[EPB];                         //  8 KB
    const int bx = blockIdx.x;
    const int t  = threadIdx.x;

    if (bx < S3B) {
        // ---- s3: partition EPB edges into bucket slabs, LDS-local sort ----
        hist[t] = 0; cur[t] = 0;
        __syncthreads();
        const int e0 = bx * EPB;
        int src[8], dst[8];
#pragma unroll
        for (int k = 0; k < 8; ++k) {
            int e = e0 + t + k * 512;
            bool valid = e < EDGES;
            src[k] = valid ? ei[e] : 0;
            dst[k] = valid ? ei[EDGES + e] : -1;
            if (valid) atomicAdd(&hist[dst[k] >> 8], 1);
        }
        __syncthreads();
        // exclusive scan of hist -> lstart: wave shfl scan + 8 partials
        int v = hist[t];
        int incl = v;
#pragma unroll
        for (int off = 1; off < 64; off <<= 1) {
            int u = __shfl_up(incl, off, 64);
            if ((t & 63) >= off) incl += u;
        }
        if ((t & 63) == 63) wsum8[t >> 6] = incl;
        __syncthreads();
        {
            int wid = t >> 6, wpre = 0;
#pragma unroll
            for (int k = 0; k < 7; ++k) if (k < wid) wpre += wsum8[k];
            lstart[t] = wpre + incl - v;
        }
        // global reservation
        if (v) gbase[t] = atomicAdd(&bcur[t], v);
        __syncthreads();
        // scatter regs -> LDS (bucket-contiguous)
#pragma unroll
        for (int k = 0; k < 8; ++k) {
            if (dst[k] >= 0) {
                int b = dst[k] >> 8;
                int pos = lstart[b] + atomicAdd(&cur[b], 1);
                ebuf[pos] = (unsigned)src[k] | ((unsigned)(dst[k] & 255) << 24);
                bk[pos] = (unsigned short)b;
            }
        }
        __syncthreads();
        // linear sweep: consecutive i -> consecutive slab addresses
        int total = EDGES - e0; if (total > EPB) total = EPB;
        for (int i = t; i < total; i += 512) {
            int b = bk[i];
            tmp[(size_t)b * CAP + gbase[b] + (i - lstart[b])] = ebuf[i];
        }
        return;
    }

    if (bx < S3B + PREPB) {
        // ---- weight prep ----
        int idx = (bx - S3B) * 512 + t;
        int layer = idx >= DIM * KTOT;
        int li = layer ? idx - DIM * KTOT : idx;
        const float* bw = layer ? bw1 : bw0;
        const float* sw = layer ? sw1 : sw0;
        const float* sc = layer ? sc1 : sc0;
        unsigned short* wt = layer ? wt1 : wt0;
        int o = li / KTOT, k = li % KTOT;
        float v;
        if (k < DIM) {
            v = bw[o * DIM + k];
        } else {
            int i = (k - DIM) >> 3, g = (k - DIM) & 7;
            v = sw[(o * DIM + i) * 8 + g] * sc[o * DIM + i];
        }
        wt[li] = __half_as_ushort(__float2half(v));
        return;
    }

    // ---- conv: x fp32 -> fp16, pad rows, graph offsets ----
    int i = (bx - S3B - PREPB) * 512 + t;
    if (i < NODES * 16) {
        float4 v = ((const float4*)x)[i];
        unsigned lo = packh2(v.x, v.y);
        unsigned hi = packh2(v.z, v.w);
        ((uint2*)xb)[i] = make_uint2(lo, hi);
        if ((i & 15) == 0) {
            int n = i >> 4;
            int b  = bat[n];
            int bp = (n == 0) ? -1 : bat[n - 1];
            for (int g = bp + 1; g <= b; ++g) goff[g] = n;
        }
        if (i == 0) {
            int blast = bat[NODES - 1];
            for (int g = blast + 1; g <= GRAPHS; ++g) goff[g] = NODES;
        }
    } else {
        int j = i - NODES * 16;
        if (j < 16)      ((uint2*)xb)[NODES * 16 + j] = make_uint2(0, 0);
        else if (j < 32) ((uint2*)hpad)[j - 16]       = make_uint2(0, 0);
    }
}

// ===========================================================================
// s4: per-bucket node-level counting sort -> rowp + padded col.
// Single global pass: stage tmp in 4 regs/thread, histogram+scatter from
// regs; 256-scan via wave shfl.
// ===========================================================================
__global__ __launch_bounds__(1024) void s4_fill(const unsigned* __restrict__ tmp,
                                                const int* __restrict__ bcur,
                                                int2* __restrict__ rowp,
                                                int* __restrict__ col) {
    __shared__ int deg[256], scanI[256], cur[256];
    __shared__ int wsum4[4];
    __shared__ int tot;
    __shared__ int4 colbuf4[CAP / 4];          // 18.4 KB
    int* colbuf = (int*)colbuf4;
    const int b = blockIdx.x, t = threadIdx.x;
    const int cnt = bcur[b];
    const int base = b * CAP;
    if (t < 256) deg[t] = 0;
    __syncthreads();

    // register-stage tmp (one global pass) + LDS histogram
    unsigned r0 = 0, r1 = 0, r2 = 0, r3 = 0;
    const int n0 = t, n1 = t + 1024, n2 = t + 2048, n3 = t + 3072;
    if (n0 < cnt) { r0 = tmp[base + n0]; atomicAdd(&deg[r0 >> 24], 1); }
    if (n1 < cnt) { r1 = tmp[base + n1]; atomicAdd(&deg[r1 >> 24], 1); }
    if (n2 < cnt) { r2 = tmp[base + n2]; atomicAdd(&deg[r2 >> 24], 1); }
    if (n3 < cnt) { r3 = tmp[base + n3]; atomicAdd(&deg[r3 >> 24], 1); }
    __syncthreads();

    // inclusive scan of padded degrees over t<256 (waves 0-3) via shfl
    int d_  = (t < 256) ? deg[t] : 0;
    int pad = (d_ + 3) & ~3;
    int incl = pad;
#pragma unroll
    for (int off = 1; off < 64; off <<= 1) {
        int u = __shfl_up(incl, off, 64);
        if ((t & 63) >= off) incl += u;
    }
    if (t < 256 && (t & 63) == 63) wsum4[t >> 6] = incl;
    __syncthreads();
    if (t < 256) {
        int wid = t >> 6, wpre = 0;
#pragma unroll
        for (int k = 0; k < 3; ++k) if (k < wid) wpre += wsum4[k];
        int sI = wpre + incl;                 // inclusive scan of pad
        scanI[t] = sI;
        int start = sI - pad;
        int ng = b * 256 + t;
        if (ng < NODES) rowp[ng] = make_int2(base + start, base + start + pad);
        cur[t] = start;
        if (t == 255) tot = sI;
    }
    __syncthreads();

    // scatter from regs into LDS colbuf
    if (n0 < cnt) colbuf[atomicAdd(&cur[r0 >> 24], 1)] = (int)(r0 & 0xFFFFFFu);
    if (n1 < cnt) colbuf[atomicAdd(&cur[r1 >> 24], 1)] = (int)(r1 & 0xFFFFFFu);
    if (n2 < cnt) colbuf[atomicAdd(&cur[r2 >> 24], 1)] = (int)(r2 & 0xFFFFFFu);
    if (n3 < cnt) colbuf[atomicAdd(&cur[r3 >> 24], 1)] = (int)(r3 & 0xFFFFFFu);
    __syncthreads();
    if (t < 256) {
        for (int k = cur[t]; k < scanI[t]; ++k) colbuf[k] = NODES;
    }
    __syncthreads();
    int nq = tot >> 2;
    int4* out4 = (int4*)(col + base);
    for (int i = t; i < nq; i += 1024) out4[i] = colbuf4[i];
    // tail sentinels (cheap insurance for any read-ahead)
    if (t < 4) col[base + tot + t] = NODES;
}

// ===========================================================================
// Fused GIN layer -- round-1 form (measured ~39.5 us): fp16 storage, fp16
// pk-add gather with 4 independent accumulators, store-out epilogue.
// R9: XCD-aware chunked block swizzle (bijective, m204 form).  Nodes are
// graph-sorted and neighbors intra-graph; a contiguous chunk of ~195 blocks
// touches ~1.6MB of x rows -> fits one XCD's 4MB L2.  Converts gather row
// loads from L3 latency to L2 latency (gather is latency-bound).
// ===========================================================================
__global__ __launch_bounds__(256, 8) void fused_layer(const unsigned short* __restrict__ xin,
                                                      const int2* __restrict__ rowp,
                                                      const int* __restrict__ col,
                                                      const unsigned short* __restrict__ wt,
                                                      unsigned short* __restrict__ out) {
    __shared__ unsigned short wt_lds[64 * WTL_STRIDE];  // 9216 B
    __shared__ unsigned short v_lds[64 * V_STRIDE];     // 9216 B

    const int t = threadIdx.x;
    // bijective XCD chunk swizzle: NW = 1563 = 8*195 + 3
    int nbase;
    {
        const int NW = (NODES + 63) / 64;          // 1563
        const int qq = NW >> 3, rr = NW & 7;       // 195, 3
        int xcd = blockIdx.x & 7, idx = blockIdx.x >> 3;
        int wg  = (xcd < rr ? xcd * (qq + 1) : rr * (qq + 1) + (xcd - rr) * qq) + idx;
        nbase = wg * 64;
    }

    // ---- prefetch W chunk 0 into registers (2 uint4 per thread) ----
    uint4 p0, p1;
    {
        int c0 = t, c1 = t + 256;
        p0 = *(const uint4*)(wt + (c0 >> 3) * KTOT + (c0 & 7) * 8);
        p1 = *(const uint4*)(wt + (c1 >> 3) * KTOT + (c1 & 7) * 8);
    }

    // ---- fused gather: v[node] = x[node] + sum_{src} x[src] (fp16 pk-add) --
    const uint4* x4 = (const uint4*)xin;
#pragma unroll
    for (int rd = 0; rd < 2; ++rd) {
        int idx  = t + rd * 256;
        int node = idx >> 3, c8 = idx & 7;
        int n = nbase + node;
        uint4 res = make_uint4(0, 0, 0, 0);
        if (n < NODES) {
            int2 be = rowp[n];
            H8 a0, a1, a2, a3;
            a0.u = x4[n * 8 + c8];                         // self term as init
            a1.u = make_uint4(0, 0, 0, 0);
            a2.u = make_uint4(0, 0, 0, 0);
            a3.u = make_uint4(0, 0, 0, 0);
            for (int p = be.x; p < be.y; p += 4) {
                int4 c4 = *(const int4*)(col + p);
                H8 r0, r1, r2, r3;
                r0.u = x4[c4.x * 8 + c8];
                r1.u = x4[c4.y * 8 + c8];
                r2.u = x4[c4.z * 8 + c8];
                r3.u = x4[c4.w * 8 + c8];
#pragma unroll
                for (int j = 0; j < 4; ++j) {
                    a0.h[j] = __hadd2(a0.h[j], r0.h[j]);
                    a1.h[j] = __hadd2(a1.h[j], r1.h[j]);
                    a2.h[j] = __hadd2(a2.h[j], r2.h[j]);
                    a3.h[j] = __hadd2(a3.h[j], r3.h[j]);
                }
            }
#pragma unroll
            for (int j = 0; j < 4; ++j)
                a0.h[j] = __hadd2(__hadd2(a0.h[j], a1.h[j]), __hadd2(a2.h[j], a3.h[j]));
            res = a0.u;
        }
        *(uint4*)(v_lds + node * V_STRIDE + c8 * 8) = res;
    }
    // write chunk 0 to LDS
    {
        int c0 = t, c1 = t + 256;
        *(uint4*)(wt_lds + (c0 >> 3) * WTL_STRIDE + (c0 & 7) * 8) = p0;
        *(uint4*)(wt_lds + (c1 >> 3) * WTL_STRIDE + (c1 & 7) * 8) = p1;
    }
    __syncthreads();

    // ---- MFMA phase ----
    const int w = t >> 6;            // wave 0..3 -> nodes 16w..16w+15
    const int l = t & 63;
    const int q = l >> 4;            // k-quad
    const int c = l & 15;            // A row (node) / B row (output)
    const unsigned short* vrow = v_lds + ((w << 4) + c) * V_STRIDE;

    frag_cd ac0 = {0.f, 0.f, 0.f, 0.f};
    frag_cd ac1 = {0.f, 0.f, 0.f, 0.f};
    frag_cd ac2 = {0.f, 0.f, 0.f, 0.f};
    frag_cd ac3 = {0.f, 0.f, 0.f, 0.f};

#define MSTEP(OFF, A) {                                                          \
        f16x8 b0 = *(const f16x8*)(wt_lds + (c     ) * WTL_STRIDE + (OFF));      \
        f16x8 b1 = *(const f16x8*)(wt_lds + (c + 16) * WTL_STRIDE + (OFF));      \
        f16x8 b2 = *(const f16x8*)(wt_lds + (c + 32) * WTL_STRIDE + (OFF));      \
        f16x8 b3 = *(const f16x8*)(wt_lds + (c + 48) * WTL_STRIDE + (OFF));      \
        ac0 = __builtin_amdgcn_mfma_f32_16x16x32_f16(A, b0, ac0, 0, 0, 0);       \
        ac1 = __builtin_amdgcn_mfma_f32_16x16x32_f16(A, b1, ac1, 0, 0, 0);       \
        ac2 = __builtin_amdgcn_mfma_f32_16x16x32_f16(A, b2, ac2, 0, 0, 0);       \
        ac3 = __builtin_amdgcn_mfma_f32_16x16x32_f16(A, b3, ac3, 0, 0, 0); }

    // prefetch chunk 1 (in flight during chunk-0 compute)
    {
        int c0 = t, c1 = t + 256;
        p0 = *(const uint4*)(wt + (c0 >> 3) * KTOT + KSTAGE + (c0 & 7) * 8);
        p1 = *(const uint4*)(wt + (c1 >> 3) * KTOT + KSTAGE + (c1 & 7) * 8);
    }

    // chunk 0: silu base features k = 0..63 (2 MFMA steps)
#pragma unroll
    for (int s = 0; s < 2; ++s) {
        f16x8 hv = *(const f16x8*)(vrow + 32 * s + 8 * q);
        float f[8];
#pragma unroll
        for (int j = 0; j < 8; ++j) f[j] = silu((float)hv[j]);
        union { f16x8 v; unsigned u[4]; } a;
#pragma unroll
        for (int j = 0; j < 4; ++j) a.u[j] = packh2(f[2 * j], f[2 * j + 1]);
        MSTEP(32 * s + 8 * q, a.v);
    }

    // chunks 1..8: barrier, commit prefetched chunk, prefetch next, 2 steps
#pragma unroll
    for (int st = 1; st < 9; ++st) {
        __syncthreads();
        {
            int c0 = t, c1 = t + 256;
            *(uint4*)(wt_lds + (c0 >> 3) * WTL_STRIDE + (c0 & 7) * 8) = p0;
            *(uint4*)(wt_lds + (c1 >> 3) * WTL_STRIDE + (c1 & 7) * 8) = p1;
        }
        __syncthreads();
        if (st < 8) {
            int c0 = t, c1 = t + 256;
            p0 = *(const uint4*)(wt + (c0 >> 3) * KTOT + (st + 1) * KSTAGE + (c0 & 7) * 8);
            p1 = *(const uint4*)(wt + (c1 >> 3) * KTOT + (st + 1) * KSTAGE + (c1 & 7) * 8);
        }
#pragma unroll
        for (int k2 = 0; k2 < 2; ++k2) {
            // dim handled by this step: d = 8*(st-1) + 4*k2 + q
            f16x8 a = bases_frag((float)(*(const _Float16*)(vrow + 8 * (st - 1) + 4 * k2 + q)));
            MSTEP(32 * k2 + 8 * q, a);
        }
    }
#undef MSTEP

    // ---- store fp16: C/D rows = nodes, cols = c + 16*acc ----
    const int n0 = nbase + (w << 4) + (q << 2);
#pragma unroll
    for (int r = 0; r < 4; ++r) {
        int n = n0 + r;
        if (n < NODES) {
            unsigned short* o = out + (size_t)n * DIM + c;
            o[0]  = __half_as_ushort(__float2half(ac0[r]));
            o[16] = __half_as_ushort(__float2half(ac1[r]));
            o[32] = __half_as_ushort(__float2half(ac2[r]));
            o[48] = __half_as_ushort(__float2half(ac3[r]));
        }
    }
}

// ---------------------------------------------------------------------------
// Fused pool + head: one block per graph, uint4 (16B/lane) h-loads.
// ---------------------------------------------------------------------------
__global__ __launch_bounds__(256) void pool_head(const unsigned short* __restrict__ h,
                                                 const int* __restrict__ goff,
                                                 const float* __restrict__ bwh,
                                                 const float* __restrict__ swh,
                                                 const float* __restrict__ sch,
                                                 float* __restrict__ out) {
    __shared__ float red[32][64];
    const int g = blockIdx.x, t = threadIdx.x;
    const int start = goff[g], end = goff[g + 1];
    const int grp = t >> 3, c8 = t & 7;
    const uint4* h4 = (const uint4*)h;

    float f[8];
#pragma unroll
    for (int j = 0; j < 8; ++j) f[j] = 0.f;
    for (int n = start + grp; n < end; n += 32) {
        H8 v; v.u = h4[n * 8 + c8];
#pragma unroll
        for (int j = 0; j < 4; ++j) {
            float2 fj = __half22float2(v.h[j]);
            f[2 * j]     += fj.x;
            f[2 * j + 1] += fj.y;
        }
    }
#pragma unroll
    for (int j = 0; j < 8; ++j) red[grp][c8 * 8 + j] = f[j];
    __syncthreads();

    if (t < 64) {
        const int i = t;
        float xv = 0.f;
#pragma unroll
        for (int k = 0; k < 32; ++k) xv += red[k][i];

        float s  = silu(xv);
        float tt  = fmaf(xv, 2.5f, 5.5f);
        float fm  = floorf(tt);
        int   m   = (int)fm;
        float u   = tt - fm;
        float u2  = u * u;
        float u3  = u2 * u;
        float v0  = fmaf(fmaf(fmaf(u, -(1.f / 6.f), 0.5f), u, -0.5f), u, 1.f / 6.f);
        float v1  = fmaf(u3, 0.5f, fmaf(u2, -1.f, 2.f / 3.f));
        float v2  = fmaf(u + u2 - u3, 0.5f, 1.f / 6.f);
        float v3  = u3 * (1.f / 6.f);
        bool inr  = (m >= 0) && (m <= 10);
        float b[8];
#pragma unroll
        for (int j = 0; j < 8; ++j) {
            float bv = 0.f;
            bv = (j == m - 3) ? v0 : bv;
            bv = (j == m - 2) ? v1 : bv;
            bv = (j == m - 1) ? v2 : bv;
            bv = (j == m)     ? v3 : bv;
            b[j] = inr ? bv : 0.f;
        }

        float part[NT];
#pragma unroll
        for (int o = 0; o < NT; ++o) {
            const float* sp = swh + (o * DIM + i) * 8;
            float sb = 0.f;
#pragma unroll
            for (int qq = 0; qq < 8; ++qq) sb = fmaf(b[qq], sp[qq], sb);
            part[o] = fmaf(s, bwh[o * DIM + i], sb * sch[o * DIM + i]);
        }
#pragma unroll
        for (int o = 0; o < NT; ++o) {
            float v = part[o];
#pragma unroll
            for (int off = 32; off > 0; off >>= 1) v += __shfl_down(v, off, 64);
            if (i == 0) out[g * NT + o] = v;
        }
    }
}

// ---------------------------------------------------------------------------
extern "C" void kernel_launch(void* const* d_in, const int* in_sizes, int n_in,
                              void* d_out, int out_size, void* d_ws, size_t ws_size,
                              hipStream_t stream) {
    const float* x   = (const float*)d_in[0];
    const int*   ei  = (const int*)d_in[1];
    const int*   bat = (const int*)d_in[2];
    const float* bw0 = (const float*)d_in[3];
    const float* sw0 = (const float*)d_in[4];
    const float* sc0 = (const float*)d_in[5];
    const float* bw1 = (const float*)d_in[6];
    const float* sw1 = (const float*)d_in[7];
    const float* sc1 = (const float*)d_in[8];
    const float* bwh = (const float*)d_in[9];
    const float* swh = (const float*)d_in[10];
    const float* sch = (const float*)d_in[11];
    float* out = (float*)d_out;

    const size_t ROW = (size_t)(NODES + 1) * DIM;   // +1 zero row for gather pad

    // ---- workspace layout (16B-aligned sections) ----
    unsigned short* wt0 = (unsigned short*)d_ws;                 // 36864 fp16
    unsigned short* wt1 = wt0 + DIM * KTOT;                      // 36864 fp16
    unsigned short* xbf = wt1 + DIM * KTOT;                      // ROW fp16
    unsigned short* hbf = xbf + ROW;                             // ROW fp16 (layer0 out)
    unsigned short* h2  = hbf + ROW;                             // NODES*DIM fp16
    int* goff     = (int*)(h2 + (size_t)NODES * DIM);            // 514 i (padded)
    int2* rowp    = (int2*)(goff + 514);                         // NODES int2
    int* col      = (int*)(rowp + NODES);                        // NB*CAP i
    int* bcur     = col + (size_t)NB * CAP;                      // NB i
    unsigned* tmp = (unsigned*)(bcur + NB);                      // NB*CAP u32

    (void)hipMemsetAsync(bcur, 0, NB * sizeof(int), stream);

    mega<<<S3B + PREPB + CONVB, 512, 0, stream>>>(
        ei, bcur, tmp,
        bw0, sw0, sc0, bw1, sw1, sc1, wt0, wt1,
        x, bat, xbf, hbf + (size_t)NODES * DIM, goff);

    s4_fill<<<NBUSED, 1024, 0, stream>>>(tmp, bcur, rowp, col);

    const int layer_blocks = (NODES + 63) / 64;        // 1563
    fused_layer<<<layer_blocks, 256, 0, stream>>>(xbf, rowp, col, wt0, hbf);
    fused_layer<<<layer_blocks, 256, 0, stream>>>(hbf, rowp, col, wt1, h2);

    pool_head<<<GRAPHS, 256, 0, stream>>>(h2, goff, bwh, swh, sch, out);
}